// Round 2
// baseline (297.539 us; speedup 1.0000x reference)
//
#include <hip/hip_runtime.h>

// Fused NCA step: perception(4 fixed 3x3 filters, wrap pad) -> 1x1 conv 32->16
// +bias+ReLU -> 1x1 conv 16->8 -> x + y*mask.
// B=16, C=8, H=W=512, HID=16. fp32 (no fp32 MFMA on CDNA4).
// R2: explicit software pipeline. R1 was latency-bound (VALUBusy 53%,
// HBM 20%): c-loop issued 9 loads -> waitcnt -> compute with no overlap.
// Now: double-buffered channel prefetch (full unroll, static buffer idx),
// early mask load, pipelined epilogue x loads. VGPR budget 128 (4 waves/SIMD,
// ILP replaces TLP).

constexpr int B = 16, C = 8, H = 512, W = 512, HID = 16;

__global__ __launch_bounds__(256, 4) void nca_step_kernel(
    const float* __restrict__ x,
    const float* __restrict__ w1w,   // [16][32]
    const float* __restrict__ w1b,   // [16]
    const float* __restrict__ w2w,   // [8][16]
    const int*   __restrict__ mask,  // [B][1][H][W]
    float*       __restrict__ out)   // [B][C][H][W]
{
    // block -> (batch, row-pair), XCD-bijective swizzle (4096 % 8 == 0):
    // each XCD gets a contiguous chunk of row-pairs -> halo rows L2-local.
    const int bid = blockIdx.x;
    const int l   = ((bid & 7) << 9) | (bid >> 3);

    const int t  = threadIdx.x;
    const int rb = t >> 7;         // row within pair
    const int tx = t & 127;        // 128 threads * 4 px = 512 = W
    const int b  = l >> 8;
    const int pr = l & 255;
    const int y  = (pr << 1) | rb;
    const int x0 = tx << 2;

    const int ym = (y - 1) & (H - 1);
    const int yp = (y + 1) & (H - 1);
    const int xl = (x0 - 1) & (W - 1);
    const int xr = (x0 + 4) & (W - 1);

    const float* xb = x + (size_t)b * C * H * W;
    const size_t o_m = (size_t)ym * W, o_c = (size_t)y * W, o_p = (size_t)yp * W;
    const size_t pix = o_c + x0;

    // mask load issued up front; latency hidden under the whole c-loop
    const int4 m4 = *(const int4*)(mask + (size_t)b * H * W + pix);

    // accumulators: 16 hidden ch x 4 px, init with bias (s_load)
    float acc[HID][4];
#pragma unroll
    for (int h = 0; h < HID; ++h) {
        const float bv = w1b[h];
#pragma unroll
        for (int p = 0; p < 4; ++p) acc[h][p] = bv;
    }

    // double-buffered channel neighborhood: 3 float4 rows + 6 edge scalars
    float4 bm[2], bc[2], bp[2];
    float  el[2][3], er[2][3];

    auto loadch = [&](int c, int s) {
        const float* xc = xb + c * H * W;
        bm[s] = *(const float4*)(xc + o_m + x0);
        bc[s] = *(const float4*)(xc + o_c + x0);
        bp[s] = *(const float4*)(xc + o_p + x0);
        el[s][0] = xc[o_m + xl]; er[s][0] = xc[o_m + xr];
        el[s][1] = xc[o_c + xl]; er[s][1] = xc[o_c + xr];
        el[s][2] = xc[o_p + xl]; er[s][2] = xc[o_p + xr];
    };

    loadch(0, 0);

#pragma unroll
    for (int c = 0; c < C; ++c) {
        const int cur = c & 1;
        if (c + 1 < C) loadch(c + 1, cur ^ 1);   // prefetch next channel

        const float cm[6] = {el[cur][0], bm[cur].x, bm[cur].y, bm[cur].z, bm[cur].w, er[cur][0]};
        const float cc[6] = {el[cur][1], bc[cur].x, bc[cur].y, bc[cur].z, bc[cur].w, er[cur][1]};
        const float cp[6] = {el[cur][2], bp[cur].x, bp[cur].y, bp[cur].z, bp[cur].w, er[cur][2]};

        // shared vertical pass: s = top + 2*mid + bot, d = bot - top
        float s[6], d[6];
#pragma unroll
        for (int i = 0; i < 6; ++i) {
            s[i] = fmaf(2.0f, cc[i], cm[i] + cp[i]);
            d[i] = cp[i] - cm[i];
        }

#pragma unroll
        for (int p = 0; p < 4; ++p) {
            const float ident = cc[p + 1];
            const float sx  = (s[p + 2] - s[p]) * 0.125f;
            const float sy  = fmaf(2.0f, d[p + 1], d[p] + d[p + 2]) * 0.125f;
            const float lap = fmaf(fmaf(2.0f, s[p + 1], s[p] + s[p + 2]),
                                   0.0625f, -ident);
            const float* wrow = w1w + c * 4;
#pragma unroll
            for (int h = 0; h < HID; ++h) {
                const float* wh = wrow + h * 32;   // uniform -> s_load
                acc[h][p] = fmaf(wh[0], ident, acc[h][p]);
                acc[h][p] = fmaf(wh[1], sx,    acc[h][p]);
                acc[h][p] = fmaf(wh[2], sy,    acc[h][p]);
                acc[h][p] = fmaf(wh[3], lap,   acc[h][p]);
            }
        }
    }

    // ReLU
#pragma unroll
    for (int h = 0; h < HID; ++h)
#pragma unroll
        for (int p = 0; p < 4; ++p) acc[h][p] = fmaxf(acc[h][p], 0.0f);

    const float mf0 = (float)m4.x, mf1 = (float)m4.y,
                mf2 = (float)m4.z, mf3 = (float)m4.w;

    float* ob = out + (size_t)b * C * H * W;

    // epilogue: pipelined residual-x loads (prefetch o+1 under o's 64 FMAs)
    float4 xo = *(const float4*)(xb + pix);
#pragma unroll
    for (int o = 0; o < C; ++o) {
        float4 xn;
        if (o + 1 < C) xn = *(const float4*)(xb + (o + 1) * H * W + pix);
        float v0 = 0.f, v1 = 0.f, v2 = 0.f, v3 = 0.f;
        const float* w2r = w2w + o * HID;
#pragma unroll
        for (int h = 0; h < HID; ++h) {
            const float wv = w2r[h];   // uniform -> s_load
            v0 = fmaf(wv, acc[h][0], v0);
            v1 = fmaf(wv, acc[h][1], v1);
            v2 = fmaf(wv, acc[h][2], v2);
            v3 = fmaf(wv, acc[h][3], v3);
        }
        float4 r;
        r.x = fmaf(v0, mf0, xo.x);
        r.y = fmaf(v1, mf1, xo.y);
        r.z = fmaf(v2, mf2, xo.z);
        r.w = fmaf(v3, mf3, xo.w);
        *(float4*)(ob + o * H * W + pix) = r;
        xo = xn;
    }
}

extern "C" void kernel_launch(void* const* d_in, const int* in_sizes, int n_in,
                              void* d_out, int out_size, void* d_ws, size_t ws_size,
                              hipStream_t stream) {
    const float* x    = (const float*)d_in[0];
    const float* w1w  = (const float*)d_in[1];
    const float* w1b  = (const float*)d_in[2];
    const float* w2w  = (const float*)d_in[3];
    const int*   mask = (const int*)d_in[4];
    float* out = (float*)d_out;

    dim3 grid(B * H / 2);   // 4096 blocks, divisible by 8 (XCD swizzle bijective)
    dim3 block(256);
    hipLaunchKernelGGL(nca_step_kernel, grid, block, 0, stream,
                       x, w1w, w1b, w2w, mask, out);
}

// Round 3
// 212.236 us; speedup vs baseline: 1.4019x; 1.4019x over previous
//
#include <hip/hip_runtime.h>

// Fused NCA step: perception(4 fixed 3x3 filters, wrap pad) -> 1x1 conv 32->16
// +bias+ReLU -> 1x1 conv 16->8 -> x + y*mask.  fp32 (no fp32 MFMA on CDNA4).
// R3: R2's software pipeline was right in theory but the lambda+array double
// buffer went to SCRATCH (rule: runtime-indexed arrays -> local mem; WRITE_SIZE
// 131->512 MB proved it). Same pipeline, now with NAMED register buffers via
// macro expansion -- every value statically addressed, hand-unrolled A/B swap.

constexpr int B = 16, C = 8, H = 512, W = 512, HID = 16;

__global__ __launch_bounds__(256, 4) void nca_step_kernel(
    const float* __restrict__ x,
    const float* __restrict__ w1w,   // [16][32]
    const float* __restrict__ w1b,   // [16]
    const float* __restrict__ w2w,   // [8][16]
    const int*   __restrict__ mask,  // [B][1][H][W]
    float*       __restrict__ out)   // [B][C][H][W]
{
    // block -> (batch, row-pair), XCD-bijective swizzle (4096 % 8 == 0)
    const int bid = blockIdx.x;
    const int l   = ((bid & 7) << 9) | (bid >> 3);

    const int t  = threadIdx.x;
    const int rb = t >> 7;
    const int tx = t & 127;        // 128 threads * 4 px = 512 = W
    const int b  = l >> 8;
    const int pr = l & 255;
    const int y  = (pr << 1) | rb;
    const int x0 = tx << 2;

    const int ym = (y - 1) & (H - 1);
    const int yp = (y + 1) & (H - 1);
    const int xl = (x0 - 1) & (W - 1);
    const int xr = (x0 + 4) & (W - 1);

    const float* xb = x + (size_t)b * C * H * W;
    const size_t o_m = (size_t)ym * W, o_c = (size_t)y * W, o_p = (size_t)yp * W;
    const size_t pix = o_c + x0;

    // mask load issued up front; latency hidden under the whole c-loop
    const int4 m4 = *(const int4*)(mask + (size_t)b * H * W + pix);

    float acc[HID][4];               // static indices only (full unroll)
#pragma unroll
    for (int h = 0; h < HID; ++h) {
        const float bv = w1b[h];
#pragma unroll
        for (int p = 0; p < 4; ++p) acc[h][p] = bv;
    }

    // ---- named double-buffer registers (NO arrays, NO lambda) ----
    float4 Am, Ac, Ap, Bm, Bc, Bp;
    float  Al0, Al1, Al2, Ar0, Ar1, Ar2;
    float  Bl0, Bl1, Bl2, Br0, Br1, Br2;

#define LOADCH(P, ch) do {                                            \
    const float* xc_ = xb + (ch) * H * W;                             \
    P##m = *(const float4*)(xc_ + o_m + x0);                          \
    P##c = *(const float4*)(xc_ + o_c + x0);                          \
    P##p = *(const float4*)(xc_ + o_p + x0);                          \
    P##l0 = xc_[o_m + xl]; P##r0 = xc_[o_m + xr];                     \
    P##l1 = xc_[o_c + xl]; P##r1 = xc_[o_c + xr];                     \
    P##l2 = xc_[o_p + xl]; P##r2 = xc_[o_p + xr]; } while (0)

#define COMPCH(P, ch) do {                                            \
    const float cm[6] = {P##l0, P##m.x, P##m.y, P##m.z, P##m.w, P##r0}; \
    const float cc[6] = {P##l1, P##c.x, P##c.y, P##c.z, P##c.w, P##r1}; \
    const float cp[6] = {P##l2, P##p.x, P##p.y, P##p.z, P##p.w, P##r2}; \
    float s_[6], d_[6];                                               \
    _Pragma("unroll") for (int i = 0; i < 6; ++i) {                   \
        s_[i] = fmaf(2.0f, cc[i], cm[i] + cp[i]);                     \
        d_[i] = cp[i] - cm[i]; }                                      \
    _Pragma("unroll") for (int p = 0; p < 4; ++p) {                   \
        const float ident = cc[p + 1];                                \
        const float sx  = (s_[p + 2] - s_[p]) * 0.125f;               \
        const float sy  = fmaf(2.0f, d_[p + 1], d_[p] + d_[p + 2]) * 0.125f; \
        const float lap = fmaf(fmaf(2.0f, s_[p + 1], s_[p] + s_[p + 2]), \
                               0.0625f, -ident);                      \
        const float* wrow = w1w + (ch) * 4;                           \
        _Pragma("unroll") for (int h = 0; h < HID; ++h) {             \
            const float* wh = wrow + h * 32;   /* uniform -> s_load */ \
            acc[h][p] = fmaf(wh[0], ident, acc[h][p]);                \
            acc[h][p] = fmaf(wh[1], sx,    acc[h][p]);                \
            acc[h][p] = fmaf(wh[2], sy,    acc[h][p]);                \
            acc[h][p] = fmaf(wh[3], lap,   acc[h][p]); } } } while (0)

    // hand-unrolled pipeline: issue next channel's loads before computing cur
    LOADCH(A, 0);
    LOADCH(B, 1); COMPCH(A, 0);
    LOADCH(A, 2); COMPCH(B, 1);
    LOADCH(B, 3); COMPCH(A, 2);
    LOADCH(A, 4); COMPCH(B, 3);
    LOADCH(B, 5); COMPCH(A, 4);
    LOADCH(A, 6); COMPCH(B, 5);
    LOADCH(B, 7); COMPCH(A, 6);
    COMPCH(B, 7);

#undef LOADCH
#undef COMPCH

    // ReLU
#pragma unroll
    for (int h = 0; h < HID; ++h)
#pragma unroll
        for (int p = 0; p < 4; ++p) acc[h][p] = fmaxf(acc[h][p], 0.0f);

    const float mf0 = (float)m4.x, mf1 = (float)m4.y,
                mf2 = (float)m4.z, mf3 = (float)m4.w;

    float* ob = out + (size_t)b * C * H * W;

    // epilogue: pipelined residual-x loads (named xo/xn, static unroll)
    float4 xo = *(const float4*)(xb + pix);
#pragma unroll
    for (int o = 0; o < C; ++o) {
        float4 xn;
        if (o + 1 < C) xn = *(const float4*)(xb + (o + 1) * H * W + pix);
        float v0 = 0.f, v1 = 0.f, v2 = 0.f, v3 = 0.f;
        const float* w2r = w2w + o * HID;
#pragma unroll
        for (int h = 0; h < HID; ++h) {
            const float wv = w2r[h];   // uniform -> s_load
            v0 = fmaf(wv, acc[h][0], v0);
            v1 = fmaf(wv, acc[h][1], v1);
            v2 = fmaf(wv, acc[h][2], v2);
            v3 = fmaf(wv, acc[h][3], v3);
        }
        float4 r;
        r.x = fmaf(v0, mf0, xo.x);
        r.y = fmaf(v1, mf1, xo.y);
        r.z = fmaf(v2, mf2, xo.z);
        r.w = fmaf(v3, mf3, xo.w);
        *(float4*)(ob + o * H * W + pix) = r;
        xo = xn;
    }
}

extern "C" void kernel_launch(void* const* d_in, const int* in_sizes, int n_in,
                              void* d_out, int out_size, void* d_ws, size_t ws_size,
                              hipStream_t stream) {
    const float* x    = (const float*)d_in[0];
    const float* w1w  = (const float*)d_in[1];
    const float* w1b  = (const float*)d_in[2];
    const float* w2w  = (const float*)d_in[3];
    const int*   mask = (const int*)d_in[4];
    float* out = (float*)d_out;

    dim3 grid(B * H / 2);   // 4096 blocks, divisible by 8 (XCD swizzle bijective)
    dim3 block(256);
    hipLaunchKernelGGL(nca_step_kernel, grid, block, 0, stream,
                       x, w1w, w1b, w2w, mask, out);
}

// Round 4
// 121.264 us; speedup vs baseline: 2.4536x; 1.7502x over previous
//
#include <hip/hip_runtime.h>

// Fused NCA step: perception(4 fixed 3x3 filters, wrap pad) -> 1x1 conv 32->16
// +bias+ReLU -> 1x1 conv 16->8 -> x + y*mask.  fp32.
// R4: (a) 2 px/thread (one row per 256-thread block) -> working set ~85 VGPR,
// no spills (R2/R3 spilled: 4px working set ~130 > budget).
// (b) v_pk_fma_f32 (packed fp32, the 157-TF path) for both 1x1 convs:
// weights pre-duplicated into float2{w,w} in d_ws by a tiny prologue kernel,
// fed as uniform SGPR-pair src0 -> 1 instr per 2 pixel-FMAs, no v_mov tax.

constexpr int B = 16, C = 8, H = 512, W = 512, HID = 16;
constexpr int HW = H * W;

// acc += w * p   (w uniform SGPR pair {w,w}, p/acc per-lane float2)
#define PKFMA_S(acc, w, p) \
    asm("v_pk_fma_f32 %0, %1, %2, %0" : "+v"(acc) : "s"(w), "v"(p))
// acc += a * b   (all VGPR)
#define PKFMA_V(acc, a, b) \
    asm("v_pk_fma_f32 %0, %1, %2, %0" : "+v"(acc) : "v"(a), "v"(b))

__global__ void repack_weights(const float* __restrict__ w1w,
                               const float* __restrict__ w2w,
                               float2* __restrict__ wd) {
    const int i = blockIdx.x * 256 + threadIdx.x;
    if (i < 512) {               // w1d[c][h][f] = dup(w1w[h][c*4+f])
        const int c = i >> 6, r = i & 63, h = r >> 2, f = r & 3;
        const float v = w1w[h * 32 + c * 4 + f];
        wd[i] = make_float2(v, v);
    } else if (i < 640) {        // w2d[o][h] = dup(w2w[o][h])
        const float v = w2w[i - 512];
        wd[i] = make_float2(v, v);
    }
}

__global__ __launch_bounds__(256, 4) void nca_step_kernel(
    const float* __restrict__ x,
    const float* __restrict__ w1b,
    const int*   __restrict__ mask,
    float*       __restrict__ out,
    const float2* __restrict__ wd)
{
    // block = one image row; XCD-bijective swizzle (8192 = 8 * 1024)
    const int bid = blockIdx.x;
    const int l   = (bid & 7) * 1024 + (bid >> 3);
    const int b   = l >> 9;
    const int y   = l & (H - 1);

    const int tx = threadIdx.x;
    const int x0 = tx << 1;                  // 2 px/thread
    const int xl = (x0 - 1) & (W - 1);
    const int xr = (x0 + 2) & (W - 1);
    const int ym = (y - 1) & (H - 1);
    const int yp = (y + 1) & (H - 1);

    const float* xb  = x + (size_t)b * C * HW;
    const int o_m = ym * W, o_cr = y * W, o_p = yp * W;
    const int pix = o_cr + x0;

    // mask early; latency hides under the channel loop
    const int2 m2 = *(const int2*)(mask + (size_t)b * HW + pix);

    float2 acc[HID];                         // 32 VGPRs, static idx (unrolled)
#pragma unroll
    for (int h = 0; h < HID; ++h) {
        const float bv = w1b[h];             // uniform -> s_load
        acc[h] = make_float2(bv, bv);
    }

#pragma unroll
    for (int c = 0; c < C; ++c) {
        const float* xc = xb + c * HW;
        const float2 vm = *(const float2*)(xc + o_m  + x0);
        const float2 vc = *(const float2*)(xc + o_cr + x0);
        const float2 vp = *(const float2*)(xc + o_p  + x0);
        const float lm = xc[o_m + xl],  rm  = xc[o_m + xr];
        const float lc = xc[o_cr + xl], rc_ = xc[o_cr + xr];
        const float lp = xc[o_p + xl],  rp  = xc[o_p + xr];

        // 4-col neighborhood; shared vertical pass
        const float cm[4] = {lm, vm.x, vm.y, rm};
        const float cc[4] = {lc, vc.x, vc.y, rc_};
        const float cp[4] = {lp, vp.x, vp.y, rp};
        float s_[4], d_[4];
#pragma unroll
        for (int i = 0; i < 4; ++i) {
            s_[i] = fmaf(2.0f, cc[i], cm[i] + cp[i]);
            d_[i] = cp[i] - cm[i];
        }
        const float i0   = cc[1], i1 = cc[2];
        const float sx0  = (s_[2] - s_[0]) * 0.125f;
        const float sx1  = (s_[3] - s_[1]) * 0.125f;
        const float sy0  = fmaf(2.0f, d_[1], d_[0] + d_[2]) * 0.125f;
        const float sy1  = fmaf(2.0f, d_[2], d_[1] + d_[3]) * 0.125f;
        const float lap0 = fmaf(fmaf(2.0f, s_[1], s_[0] + s_[2]), 0.0625f, -i0);
        const float lap1 = fmaf(fmaf(2.0f, s_[2], s_[1] + s_[3]), 0.0625f, -i1);
        const float2 idn2 = make_float2(i0, i1);
        const float2 sx2  = make_float2(sx0, sx1);
        const float2 sy2  = make_float2(sy0, sy1);
        const float2 lp2  = make_float2(lap0, lap1);

        const float2* wch = wd + c * 64;     // uniform weight slice
#pragma unroll
        for (int h = 0; h < HID; ++h) {
            const float2 w0 = wch[h * 4 + 0];
            const float2 w1 = wch[h * 4 + 1];
            const float2 w2_ = wch[h * 4 + 2];
            const float2 w3 = wch[h * 4 + 3];
            PKFMA_S(acc[h], w0, idn2);
            PKFMA_S(acc[h], w1, sx2);
            PKFMA_S(acc[h], w2_, sy2);
            PKFMA_S(acc[h], w3, lp2);
        }
    }

    // ReLU
#pragma unroll
    for (int h = 0; h < HID; ++h) {
        acc[h].x = fmaxf(acc[h].x, 0.0f);
        acc[h].y = fmaxf(acc[h].y, 0.0f);
    }

    const float2 mf = make_float2((float)m2.x, (float)m2.y);
    const float2* w2d = wd + 512;
    float* ob = out + (size_t)b * C * HW;

#pragma unroll
    for (int o = 0; o < C; ++o) {
        float2 v = make_float2(0.0f, 0.0f);
#pragma unroll
        for (int h = 0; h < HID; ++h)
            PKFMA_S(v, w2d[o * 16 + h], acc[h]);
        float2 r = *(const float2*)(xb + o * HW + pix);   // residual x
        PKFMA_V(r, v, mf);                                // r += v * mask
        *(float2*)(ob + o * HW + pix) = r;
    }
}

extern "C" void kernel_launch(void* const* d_in, const int* in_sizes, int n_in,
                              void* d_out, int out_size, void* d_ws, size_t ws_size,
                              hipStream_t stream) {
    const float* x    = (const float*)d_in[0];
    const float* w1w  = (const float*)d_in[1];
    const float* w1b  = (const float*)d_in[2];
    const float* w2w  = (const float*)d_in[3];
    const int*   mask = (const int*)d_in[4];
    float* out = (float*)d_out;
    float2* wd = (float2*)d_ws;              // 640 * 8 B = 5 KiB scratch

    hipLaunchKernelGGL(repack_weights, dim3(3), dim3(256), 0, stream,
                       w1w, w2w, wd);
    hipLaunchKernelGGL(nca_step_kernel, dim3(B * H), dim3(256), 0, stream,
                       x, w1b, mask, out, wd);
}